// Round 18
// baseline (1090.696 us; speedup 1.0000x reference)
//
#include <hip/hip_runtime.h>

// Fused flash-style softmax(Q V^T) V, B=4, NQ=NK=4096, D=1024, fp32 in/out.
// Round 18: supertile hybrid = r12's k-sliced structure (wave owns 32k x
// full-D contraction -> scores in REGISTERS, no spart; softmax chain once
// per 256k; 2 barriers per 256k) + r15's fp16 V prepass (v16/vt16) + r17's
// cross-tile pipelining (region1 = PV(i-1) || QK^T(i), interleaved per-ks).
//   region1_i: [rescale; for ks: QKT-chunk(i) ; PV-chunk(i-1)]; mx-write -> BAR
//   region2_i: register softmax(i) (defer-max, per-lane) -> p_lds[i&1] -> BAR
// Q lives in LDS (fp16, loaded once). p_lds double-buffered; mx/alr single
// (each write->read spans one barrier; next write >=1 barrier later).

#define NB   4
#define NQL  4096
#define NKL  4096
#define DIM  1024
#define BQ   32
#define SK   256
#define NW   8
#define NST  (NKL / SK)    // 16
#define LOG2E 1.44269504088896340736f
#define QLP  1032          // q_lds row stride (shorts): 2064B ≡ 4 dw mod 32 banks
#define PLP  264           // p_lds row stride (shorts): 528B ≡ 4 dw mod 32 banks
#define MXW  12

typedef float f32x4 __attribute__((ext_vector_type(4)));
typedef _Float16 f16x8 __attribute__((ext_vector_type(8)));
typedef short s16x8 __attribute__((ext_vector_type(8)));
typedef short s16x4 __attribute__((ext_vector_type(4)));

union Frag { f16x8 v; s16x8 s; _Float16 h[8]; };

__device__ __forceinline__ void rawbar() {  // LDS visibility only
    asm volatile("s_waitcnt lgkmcnt(0)\n\ts_barrier" ::: "memory");
}

// ---------------- Prepass: V fp32 -> V16 (row-major) + VT16 (transposed) -----
__global__ void prep_v(const float* __restrict__ Vg, short* __restrict__ v16,
                       short* __restrict__ vt16) {
    __shared__ short lds[64][72];
    const int t   = (int)threadIdx.x;
    const int blk = (int)blockIdx.x;
    const int bb    = blk >> 10;
    const int ktile = (blk >> 4) & 63;
    const int dtile = blk & 15;
    const int k0 = ktile * 64, d0 = dtile * 64;
    const int row = t >> 2;
    const int cb  = (t & 3) * 16;

    const float* src = Vg + ((size_t)(bb * NKL + k0 + row) * DIM + d0 + cb);
    short* vdst = v16 + ((size_t)(bb * NKL + k0 + row) * DIM + d0 + cb);
#pragma unroll
    for (int i = 0; i < 4; ++i) {
        f32x4 x = *(const f32x4*)(src + i * 4);
        s16x4 h;
#pragma unroll
        for (int j = 0; j < 4; ++j)
            h[j] = __builtin_bit_cast(short, (_Float16)x[j]);
        *(s16x4*)(vdst + i * 4) = h;
        *(s16x4*)&lds[row][cb + i * 4] = h;
    }
    __syncthreads();
    short* tdst = vt16 + ((size_t)(bb * DIM + d0 + row) * NKL + k0 + cb);
#pragma unroll
    for (int i = 0; i < 4; ++i) {
        s16x4 h;
#pragma unroll
        for (int j = 0; j < 4; ++j)
            h[j] = lds[cb + i * 4 + j][row];
        *(s16x4*)(tdst + i * 4) = h;
    }
}

// ---------------- Main kernel -------------------------------------------------
template<int MODE>
__global__ __attribute__((amdgpu_flat_work_group_size(512, 512),
                          amdgpu_waves_per_eu(2, 4)))
void attn_st(const float* __restrict__ Qg, const float* __restrict__ Vg,
             float* __restrict__ Og, const short* __restrict__ v16,
             const short* __restrict__ vt16) {
    __shared__ __align__(16) short q_lds[BQ * QLP];      // 66048 B
    __shared__ __align__(16) short p_lds[2][BQ * PLP];   // 33792 B
    __shared__ __align__(16) float mx[BQ][MXW];          // 1536 B
    __shared__ float alr[BQ];
    __shared__ __align__(16) float lsum[BQ][MXW];
    __shared__ float linv[BQ];

    const int tid = (int)threadIdx.x;
    const int l   = tid & 63;
    const int w   = tid >> 6;
    const int l15 = l & 15;
    const int lg  = l >> 4;

    // XCD-aware swizzle (512 blocks, 8 XCDs, bijective)
    const int bid  = (int)blockIdx.x;
    const int orig = (bid & 7) * 64 + (bid >> 3);
    const int b  = orig >> 7;
    const int qt = orig & 127;
    const int q0 = qt * BQ;
    const int dw = w * 128;

    // Prologue: Q[q0..q0+32][0..1024) fp32 -> fp16 into q_lds (r12-verified)
    {
        const float* qsrc = Qg + (size_t)(b * NQL + q0) * DIM;
#pragma unroll
        for (int it = 0; it < 16; ++it) {
            const int f = (it * 512 + tid) * 4;
            f32x4 x = *(const f32x4*)(qsrc + f);
            const int row = f >> 10, col = f & 1023;
            s16x4 h;
#pragma unroll
            for (int j = 0; j < 4; ++j)
                h[j] = __builtin_bit_cast(short, (_Float16)x[j]);
            *(s16x4*)&q_lds[row * QLP + col] = h;
        }
    }

    f32x4 oacc[2][8];
#pragma unroll
    for (int qb = 0; qb < 2; ++qb)
#pragma unroll
        for (int dg = 0; dg < 8; ++dg)
            oacc[qb][dg] = (f32x4){0.f, 0.f, 0.f, 0.f};

    f32x4 sacc[2][2];
    float m_reg[2]  = {-3e38f, -3e38f};
    float l_lane[2] = {0.f, 0.f};

    __syncthreads();   // q_lds ready

    // ---- QK^T chunk: dc in [ks*4, ks*4+4), wave k-slice [i*SK+32w, +32)
    auto qkt_chunk = [&](int i, int ks) {
        const int krow = b * NKL + i * SK + w * 32 + l15;
#pragma unroll
        for (int dc2 = 0; dc2 < 4; ++dc2) {
            const int dc = ks * 4 + dc2;
            Frag q0f, q1f;
            q0f.s = *(const s16x8*)&q_lds[l15 * QLP + dc * 32 + lg * 8];
            q1f.s = *(const s16x8*)&q_lds[(16 + l15) * QLP + dc * 32 + lg * 8];
#pragma unroll
            for (int kb = 0; kb < 2; ++kb) {
                Frag fa;
                if constexpr (MODE == 1) {
                    fa.s = *(const s16x8*)(v16 + (size_t)(krow + kb * 16) * DIM
                                         + dc * 32 + lg * 8);
                } else {
                    const float* vp = Vg + (size_t)(krow + kb * 16) * DIM
                                    + dc * 32 + lg * 8;
                    f32x4 x0 = *(const f32x4*)vp;
                    f32x4 x1 = *(const f32x4*)(vp + 4);
#pragma unroll
                    for (int j = 0; j < 4; ++j) {
                        fa.h[j]     = (_Float16)x0[j];
                        fa.h[j + 4] = (_Float16)x1[j];
                    }
                }
                sacc[kb][0] = __builtin_amdgcn_mfma_f32_16x16x32_f16(fa.v, q0f.v, sacc[kb][0], 0, 0, 0);
                sacc[kb][1] = __builtin_amdgcn_mfma_f32_16x16x32_f16(fa.v, q1f.v, sacc[kb][1], 0, 0, 0);
            }
        }
    };

    // ---- PV chunk ks of supertile j (d-slice dw), reads p_lds[buf]
    auto pv_chunk = [&](int j, int buf, int ks) {
        Frag pf0, pf1;
        pf0.s = *(const s16x8*)&p_lds[buf][l15 * PLP + ks * 32 + lg * 8];
        pf1.s = *(const s16x8*)&p_lds[buf][(16 + l15) * PLP + ks * 32 + lg * 8];
#pragma unroll
        for (int dg = 0; dg < 8; ++dg) {
            Frag bf;
            if constexpr (MODE == 1) {
                bf.s = *(const s16x8*)(vt16 + (size_t)(b * DIM + dw + dg * 16 + l15) * NKL
                                     + j * SK + ks * 32 + lg * 8);
            } else {
                const float* vb32 = Vg + (size_t)(b * NKL + j * SK + ks * 32 + lg * 8) * DIM
                                  + dw + l15;
#pragma unroll
                for (int jj = 0; jj < 8; ++jj)
                    bf.h[jj] = (_Float16)vb32[(size_t)jj * DIM + dg * 16];
            }
            __builtin_amdgcn_s_setprio(1);
            oacc[0][dg] = __builtin_amdgcn_mfma_f32_16x16x32_f16(pf0.v, bf.v, oacc[0][dg], 0, 0, 0);
            oacc[1][dg] = __builtin_amdgcn_mfma_f32_16x16x32_f16(pf1.v, bf.v, oacc[1][dg], 0, 0, 0);
            __builtin_amdgcn_s_setprio(0);
        }
    };

    auto pv_rescale = [&]() {
        f32x4 av0 = *(const f32x4*)&alr[lg * 4];
        f32x4 av1 = *(const f32x4*)&alr[16 + lg * 4];
        bool one = true;
#pragma unroll
        for (int r = 0; r < 4; ++r)
            one = one && (av0[r] == 1.0f) && (av1[r] == 1.0f);
        if (!__all(one)) {
#pragma unroll
            for (int dg = 0; dg < 8; ++dg)
#pragma unroll
                for (int r = 0; r < 4; ++r) {
                    oacc[0][dg][r] *= av0[r];
                    oacc[1][dg][r] *= av1[r];
                }
        }
    };

    auto mx_write = [&]() {
        float tm[2];
#pragma unroll
        for (int qb = 0; qb < 2; ++qb) {
            float t = sacc[0][qb][0];
#pragma unroll
            for (int r = 1; r < 4; ++r) t = fmaxf(t, sacc[0][qb][r]);
#pragma unroll
            for (int r = 0; r < 4; ++r) t = fmaxf(t, sacc[1][qb][r]);
            t = fmaxf(t, __shfl_xor(t, 16));
            t = fmaxf(t, __shfl_xor(t, 32));
            tm[qb] = t;
        }
        if (lg == 0) { mx[l15][w] = tm[0]; mx[16 + l15][w] = tm[1]; }
    };

    // ---- register softmax over supertile i (defer-max, per-lane; r12-verified)
    auto softmax_st = [&](int buf) {
        float alpha[2];
#pragma unroll
        for (int qb = 0; qb < 2; ++qb) {
            const int q = qb * 16 + l15;
            f32x4 ma = *(const f32x4*)&mx[q][0];
            f32x4 mb = *(const f32x4*)&mx[q][4];
            float tm = fmaxf(fmaxf(fmaxf(ma[0], ma[1]), fmaxf(ma[2], ma[3])),
                             fmaxf(fmaxf(mb[0], mb[1]), fmaxf(mb[2], mb[3])));
            const bool defer = (tm - m_reg[qb] <= 8.0f);
            const float mn = fmaxf(m_reg[qb], tm);
            const float mnew = defer ? m_reg[qb] : mn;
            alpha[qb] = defer ? 1.0f : exp2f((m_reg[qb] - mn) * LOG2E);
            m_reg[qb] = mnew;

            float psum = 0.f;
#pragma unroll
            for (int kb = 0; kb < 2; ++kb) {
                s16x4 pk;
#pragma unroll
                for (int r = 0; r < 4; ++r) {
                    float p = exp2f((sacc[kb][qb][r] - mnew) * LOG2E);
                    psum += p;
                    pk[r] = __builtin_bit_cast(short, (_Float16)p);
                }
                *(s16x4*)&p_lds[buf][q * PLP + w * 32 + kb * 16 + lg * 4] = pk;
            }
            l_lane[qb] = alpha[qb] * l_lane[qb] + psum;
        }
        if (lg == 0) { alr[l15] = alpha[0]; alr[16 + l15] = alpha[1]; }
    };

    auto sacc_zero = [&]() {
#pragma unroll
        for (int kb = 0; kb < 2; ++kb)
#pragma unroll
            for (int qb = 0; qb < 2; ++qb)
                sacc[kb][qb] = (f32x4){0.f, 0.f, 0.f, 0.f};
    };

    // ---- Supertile 0: QK^T only
    sacc_zero();
#pragma unroll 2
    for (int ks = 0; ks < 8; ++ks) qkt_chunk(0, ks);
    mx_write();
    rawbar();
    softmax_st(0);
    rawbar();

    // ---- Pipelined main loop: region1 = PV(i-1) || QK^T(i); region2 = softmax(i)
    for (int i = 1; i < NST; ++i) {
        const int pbp = (i - 1) & 1;
        pv_rescale();
        sacc_zero();
#pragma unroll 2
        for (int ks = 0; ks < 8; ++ks) {
            qkt_chunk(i, ks);
            pv_chunk(i - 1, pbp, ks);
        }
        mx_write();
        rawbar();
        softmax_st(i & 1);
        rawbar();
    }

    // ---- Tail: PV(NST-1)
    pv_rescale();
#pragma unroll 2
    for (int ks = 0; ks < 8; ++ks) pv_chunk(NST - 1, (NST - 1) & 1, ks);

    // ---- Epilogue: block-reduce l, normalize, store (r12-verified)
    {
        float lr0 = l_lane[0], lr1 = l_lane[1];
        lr0 += __shfl_xor(lr0, 16); lr0 += __shfl_xor(lr0, 32);
        lr1 += __shfl_xor(lr1, 16); lr1 += __shfl_xor(lr1, 32);
        if (lg == 0) { lsum[l15][w] = lr0; lsum[16 + l15][w] = lr1; }
    }
    __syncthreads();
    if (tid < BQ) {
        float s = 0.f;
#pragma unroll
        for (int w2 = 0; w2 < 8; ++w2) s += lsum[tid][w2];
        linv[tid] = 1.0f / s;
    }
    __syncthreads();
    {
        f32x4 il0 = *(const f32x4*)&linv[lg * 4];
        f32x4 il1 = *(const f32x4*)&linv[16 + lg * 4];
#pragma unroll
        for (int qb = 0; qb < 2; ++qb)
#pragma unroll
            for (int dg = 0; dg < 8; ++dg)
#pragma unroll
                for (int r = 0; r < 4; ++r) {
                    const int q = q0 + qb * 16 + lg * 4 + r;
                    const int d = dw + dg * 16 + l15;
                    const float sc = (qb == 0) ? il0[r] : il1[r];
                    Og[(size_t)(b * NQL + q) * DIM + d] = oacc[qb][dg][r] * sc;
                }
    }
}

extern "C" void kernel_launch(void* const* d_in, const int* in_sizes, int n_in,
                              void* d_out, int out_size, void* d_ws, size_t ws_size,
                              hipStream_t stream) {
    const float* Q = (const float*)d_in[0];
    const float* V = (const float*)d_in[1];
    float* O = (float*)d_out;
    (void)in_sizes; (void)n_in; (void)out_size;

    const size_t elems = (size_t)NB * NKL * DIM;          // 16.78M
    const size_t need  = 2 * elems * sizeof(short);       // 64 MB
    dim3 grid(NB * (NQL / BQ));  // 512 blocks
    dim3 block(NW * 64);         // 512 threads
    if (ws_size >= need) {
        short* v16  = (short*)d_ws;
        short* vt16 = v16 + elems;
        prep_v<<<dim3(NB * 1024), dim3(256), 0, stream>>>(V, v16, vt16);
        attn_st<1><<<grid, block, 0, stream>>>(Q, V, O, v16, vt16);
    } else {
        attn_st<0><<<grid, block, 0, stream>>>(Q, V, O, nullptr, nullptr);
    }
}

// Round 19
// 937.110 us; speedup vs baseline: 1.1639x; 1.1639x over previous
//
#include <hip/hip_runtime.h>

// Fused flash-style softmax(Q V^T) V, B=4, NQ=NK=4096, D=1024, fp32 in/out.
// Round 19: r17 VERBATIM except amdgpu_waves_per_eu(1,4).
// Allocator law (r13/r14/r15 data): VGPR budget = 256/min_waves_per_eu.
// r17's live-state wish-list (oacc 64 + qf 32 + staging 32 + pvreg 32 +
// sacc 16 ~ 176) exceeded its 128 budget -> compiler sank BOTH prefetches
// (VGPR_Count read 104). min=1 -> 256 budget; ~180 regs still allows
// 2 waves/SIMD (m69: cliff at 256), so occupancy is unchanged and the
// staging + vt16 prefetches finally stay live across their regions.
// Pipeline (1 barrier/tile):
//   region A_i: QK^T(i) -> spart[i&1] || vt16 loads(i-1) || softmax(i-1)
//   barrier_i
//   region B_i: PV(i-1)   (flows into A_{i+1} with no barrier)

#define NB   4
#define NQL  4096
#define NKL  4096
#define DIM  1024
#define BQ   32
#define BK   32
#define NW   8
#define DSL  128
#define NT   (NKL / BK)
#define LOG2E 1.44269504088896340736f
#define PBW  40            // pbuf row stride in shorts (80 B)

typedef float f32x2 __attribute__((ext_vector_type(2)));
typedef float f32x4 __attribute__((ext_vector_type(4)));
typedef _Float16 f16x8 __attribute__((ext_vector_type(8)));
typedef short s16x8 __attribute__((ext_vector_type(8)));
typedef short s16x4 __attribute__((ext_vector_type(4)));
typedef unsigned int uint_;

union Frag { f16x8 v; s16x8 s; _Float16 h[8]; };

__device__ __forceinline__ void rawbar() {  // LDS visibility only
    asm volatile("s_waitcnt lgkmcnt(0)\n\ts_barrier" ::: "memory");
}

// ---------------- Prepass: V fp32 -> V16 (same layout) + VT16 (transposed) ----
__global__ void prep_v(const float* __restrict__ Vg, short* __restrict__ v16,
                       short* __restrict__ vt16) {
    __shared__ short lds[64][72];
    const int t   = (int)threadIdx.x;
    const int blk = (int)blockIdx.x;
    const int bb    = blk >> 10;
    const int ktile = (blk >> 4) & 63;
    const int dtile = blk & 15;
    const int k0 = ktile * 64, d0 = dtile * 64;
    const int row = t >> 2;
    const int cb  = (t & 3) * 16;

    const float* src = Vg + ((size_t)(bb * NKL + k0 + row) * DIM + d0 + cb);
    short* vdst = v16 + ((size_t)(bb * NKL + k0 + row) * DIM + d0 + cb);
#pragma unroll
    for (int i = 0; i < 4; ++i) {
        f32x4 x = *(const f32x4*)(src + i * 4);
        s16x4 h;
#pragma unroll
        for (int j = 0; j < 4; ++j)
            h[j] = __builtin_bit_cast(short, (_Float16)x[j]);
        *(s16x4*)(vdst + i * 4) = h;
        *(s16x4*)&lds[row][cb + i * 4] = h;
    }
    __syncthreads();
    short* tdst = vt16 + ((size_t)(bb * DIM + d0 + row) * NKL + k0 + cb);
#pragma unroll
    for (int i = 0; i < 4; ++i) {
        s16x4 h;
#pragma unroll
        for (int j = 0; j < 4; ++j)
            h[j] = lds[cb + i * 4 + j][row];
        *(s16x4*)(tdst + i * 4) = h;
    }
}

// ---------------- Main kernel (MODE 1 = fp16 prepass; MODE 0 = fp32 direct) --
template<int MODE>
__global__ __attribute__((amdgpu_flat_work_group_size(512, 512),
                          amdgpu_waves_per_eu(1, 4)))
void attn_f16(const float* __restrict__ Qg, const float* __restrict__ Vg,
              float* __restrict__ Og, const short* __restrict__ v16,
              const short* __restrict__ vt16) {
    __shared__ float spart[2][NW][BQ][BK];                // 64 KB, double-buffered
    __shared__ __align__(16) short pbuf[2][BQ * PBW];     // 5 KB
    __shared__ float arun[2][BQ];
    __shared__ float lsum[BQ];

    const int tid = (int)threadIdx.x;
    const int l   = tid & 63;
    const int w   = tid >> 6;
    const int l15 = l & 15;
    const int lg  = l >> 4;

    // XCD-aware swizzle (512 blocks, 8 XCDs, bijective)
    const int bid  = (int)blockIdx.x;
    const int orig = (bid & 7) * 64 + (bid >> 3);
    const int b  = orig >> 7;
    const int qt = orig & 127;
    const int q0 = qt * BQ;
    const int dw = w * DSL;

    // Q fragments (B-operand), fp32->fp16 once per block
    f16x8 qf[2][4];
#pragma unroll
    for (int qb = 0; qb < 2; ++qb)
#pragma unroll
        for (int dc = 0; dc < 4; ++dc) {
            const float* qp = Qg + (size_t)(b * NQL + q0 + qb * 16 + l15) * DIM
                            + dw + dc * 32 + lg * 8;
            f32x4 x0 = *(const f32x4*)qp;
            f32x4 x1 = *(const f32x4*)(qp + 4);
            f16x8 a;
#pragma unroll
            for (int j = 0; j < 4; ++j) { a[j] = (_Float16)x0[j]; a[j + 4] = (_Float16)x1[j]; }
            qf[qb][dc] = a;
        }

    f32x4 oacc[2][8];
#pragma unroll
    for (int qb = 0; qb < 2; ++qb)
#pragma unroll
        for (int dg = 0; dg < 8; ++dg)
            oacc[qb][dg] = (f32x4){0.f, 0.f, 0.f, 0.f};

    f32x4 sacc[2][2];
    f32x4 hA32[4][2], hB32[4][2];   // MODE 0 staging
    s16x8 hA16[4], hB16[4];         // MODE 1 staging

    auto loadstage = [&](int buf, int kt_, int kb) {
        if constexpr (MODE == 1) {
            const short* vp = v16 + ((size_t)(b * NKL + kt_ * BK + kb * 16 + l15) * DIM
                            + dw + lg * 8);
            s16x8 (&hb)[4] = buf ? hB16 : hA16;
#pragma unroll
            for (int dc = 0; dc < 4; ++dc)
                hb[dc] = *(const s16x8*)(vp + dc * 32);
        } else {
            const float* vp = Vg + (size_t)(b * NKL + kt_ * BK + kb * 16 + l15) * DIM
                            + dw + lg * 8;
            f32x4 (&hb)[4][2] = buf ? hB32 : hA32;
#pragma unroll
            for (int dc = 0; dc < 4; ++dc) {
                hb[dc][0] = *(const f32x4*)(vp + dc * 32);
                hb[dc][1] = *(const f32x4*)(vp + dc * 32 + 4);
            }
        }
    };

    auto qkt_half = [&](int buf, int kb) {
#pragma unroll
        for (int dc = 0; dc < 4; ++dc) {
            Frag fa;
            if constexpr (MODE == 1) {
                fa.s = buf ? hB16[dc] : hA16[dc];
            } else {
                f32x4 (&hb)[4][2] = buf ? hB32 : hA32;
#pragma unroll
                for (int j = 0; j < 4; ++j) {
                    fa.h[j]     = (_Float16)hb[dc][0][j];
                    fa.h[j + 4] = (_Float16)hb[dc][1][j];
                }
            }
            sacc[kb][0] = __builtin_amdgcn_mfma_f32_16x16x32_f16(fa.v, qf[0][dc], sacc[kb][0], 0, 0, 0);
            sacc[kb][1] = __builtin_amdgcn_mfma_f32_16x16x32_f16(fa.v, qf[1][dc], sacc[kb][1], 0, 0, 0);
        }
    };

    auto qkt_tile = [&](int kt_, int spbuf) {
#pragma unroll
        for (int kb = 0; kb < 2; ++kb)
#pragma unroll
            for (int qb = 0; qb < 2; ++qb)
                sacc[kb][qb] = (f32x4){0.f, 0.f, 0.f, 0.f};
        const int ktn = (kt_ + 1 < NT) ? kt_ + 1 : NT - 1;
        qkt_half(0, 0);
        loadstage(0, ktn, 0);
        qkt_half(1, 1);
        loadstage(1, ktn, 1);
#pragma unroll
        for (int kb = 0; kb < 2; ++kb)
#pragma unroll
            for (int qb = 0; qb < 2; ++qb) {
                const int q = qb * 16 + l15;
                const int kblk = (kb * 16 + lg * 4) ^ ((q & 7) << 2);
                *(f32x4*)&spart[spbuf][w][q][kblk] = sacc[kb][qb];
            }
    };

    // softmax assignment: lane handles q = 4w+lg, k-pair {2*l15, 2*l15+1}
    const int qsm = 4 * w + lg;
    const int kk  = (2 * l15) ^ ((qsm & 7) << 2);

    float m_reg  = -3e38f;
    float l_lane = 0.f;

    auto softmax_tile = [&](int cur) {
        f32x2 sp = (f32x2){0.f, 0.f};
#pragma unroll
        for (int wv = 0; wv < NW; ++wv)
            sp += *(const f32x2*)&spart[cur][wv][qsm][kk];
        float s0 = sp[0], s1 = sp[1];
        float smax = fmaxf(s0, s1);
        float alpha = 1.0f;
        if (!__all(smax - m_reg <= 8.0f)) {
            float mloc = smax;
#pragma unroll
            for (int off = 1; off < 16; off <<= 1)
                mloc = fmaxf(mloc, __shfl_xor(mloc, off));
            float mnew = fmaxf(m_reg, mloc);
            alpha = exp2f((m_reg - mnew) * LOG2E);
            m_reg = mnew;
        }
        float p0 = exp2f((s0 - m_reg) * LOG2E);
        float p1 = exp2f((s1 - m_reg) * LOG2E);
        l_lane = alpha * l_lane + (p0 + p1);
        if (l15 == 0) arun[cur][qsm] = alpha;
        uint_ pk = (uint_)__builtin_bit_cast(unsigned short, (_Float16)p0)
                 | ((uint_)__builtin_bit_cast(unsigned short, (_Float16)p1) << 16);
        *(uint_*)&pbuf[cur][qsm * PBW + 2 * l15] = pk;
    };

    s16x8 pvreg[8];                 // MODE 1: vt16 frags preloaded in region A
    float pv32[8][8];               // MODE 0: fp32 gather (region B)

    auto pv_loads = [&](int kt_) {
        if constexpr (MODE == 1) {
            const short* vtb = vt16 + ((size_t)(b * DIM + dw + l15) * NKL
                             + kt_ * BK + lg * 8);
#pragma unroll
            for (int dg = 0; dg < 8; ++dg)
                pvreg[dg] = *(const s16x8*)(vtb + (size_t)dg * 16 * NKL);
        }
    };

    auto pv_tile = [&](int kt_, int cur) {
        if constexpr (MODE == 0) {
            const float* vb = Vg + (size_t)(b * NKL + kt_ * BK + lg * 8) * DIM
                            + dw + l15;
#pragma unroll
            for (int dg = 0; dg < 8; ++dg)
#pragma unroll
                for (int j = 0; j < 8; ++j)
                    pv32[dg][j] = vb[(size_t)j * DIM + dg * 16];
        }
        f32x4 av[2];
#pragma unroll
        for (int qb = 0; qb < 2; ++qb)
            av[qb] = *(const f32x4*)&arun[cur][qb * 16 + lg * 4];
        bool mine1 = true;
#pragma unroll
        for (int qb = 0; qb < 2; ++qb)
#pragma unroll
            for (int r = 0; r < 4; ++r)
                mine1 = mine1 && (av[qb][r] == 1.0f);
        if (!__all(mine1)) {
#pragma unroll
            for (int qb = 0; qb < 2; ++qb)
#pragma unroll
                for (int dg = 0; dg < 8; ++dg)
#pragma unroll
                    for (int r = 0; r < 4; ++r)
                        oacc[qb][dg][r] *= av[qb][r];
        }
        Frag pf[2];
#pragma unroll
        for (int qb = 0; qb < 2; ++qb)
            pf[qb].s = *(const s16x8*)&pbuf[cur][(qb * 16 + l15) * PBW + lg * 8];
#pragma unroll
        for (int dg = 0; dg < 8; ++dg) {
            Frag bf;
            if constexpr (MODE == 1) {
                bf.s = pvreg[dg];
            } else {
#pragma unroll
                for (int j = 0; j < 8; ++j)
                    bf.h[j] = (_Float16)pv32[dg][j];
            }
            __builtin_amdgcn_s_setprio(1);
#pragma unroll
            for (int qb = 0; qb < 2; ++qb)
                oacc[qb][dg] = __builtin_amdgcn_mfma_f32_16x16x32_f16(
                    pf[qb].v, bf.v, oacc[qb][dg], 0, 0, 0);
            __builtin_amdgcn_s_setprio(0);
        }
    };

    // ---- Prologue: stage tile 0, QK^T(0) -> spart[0], barrier
    loadstage(0, 0, 0);
    loadstage(1, 0, 1);
    qkt_tile(0, 0);
    rawbar();

    // ---- Pipelined main loop: one barrier per tile
    for (int kt = 1; kt < NT; ++kt) {
        const int cur = (kt - 1) & 1;
        // region A: QK^T(kt) -> spart[kt&1] || PV loads(kt-1) || softmax(kt-1)
        pv_loads(kt - 1);
        qkt_tile(kt, kt & 1);
        softmax_tile(cur);
        rawbar();
        // region B: PV(kt-1); flows into next region A without a barrier
        pv_tile(kt - 1, cur);
    }

    // ---- Tail: softmax + PV for tile NT-1
    {
        const int cur = (NT - 1) & 1;
        pv_loads(NT - 1);
        softmax_tile(cur);
        rawbar();
        pv_tile(NT - 1, cur);
    }

    // ---- Epilogue: reduce l across the 16-lane group, normalize, store
    {
        float rs = l_lane;
#pragma unroll
        for (int off = 1; off < 16; off <<= 1)
            rs += __shfl_xor(rs, off);
        if (l15 == 0) lsum[qsm] = rs;
    }
    __syncthreads();
#pragma unroll
    for (int qb = 0; qb < 2; ++qb) {
        f32x4 lv = *(const f32x4*)&lsum[qb * 16 + lg * 4];
        float il[4];
#pragma unroll
        for (int r = 0; r < 4; ++r) il[r] = 1.0f / lv[r];
#pragma unroll
        for (int dg = 0; dg < 8; ++dg)
#pragma unroll
            for (int r = 0; r < 4; ++r) {
                int q = q0 + qb * 16 + lg * 4 + r;
                int d = dw + dg * 16 + l15;
                Og[(size_t)(b * NQL + q) * DIM + d] = oacc[qb][dg][r] * il[r];
            }
    }
}

extern "C" void kernel_launch(void* const* d_in, const int* in_sizes, int n_in,
                              void* d_out, int out_size, void* d_ws, size_t ws_size,
                              hipStream_t stream) {
    const float* Q = (const float*)d_in[0];
    const float* V = (const float*)d_in[1];
    float* O = (float*)d_out;
    (void)in_sizes; (void)n_in; (void)out_size;

    const size_t elems = (size_t)NB * NKL * DIM;          // 16.78M
    const size_t need  = 2 * elems * sizeof(short);       // 64 MB
    dim3 grid(NB * (NQL / BQ));  // 512 blocks
    dim3 block(NW * 64);         // 512 threads
    if (ws_size >= need) {
        short* v16  = (short*)d_ws;
        short* vt16 = v16 + elems;
        prep_v<<<dim3(NB * 1024), dim3(256), 0, stream>>>(V, v16, vt16);
        attn_f16<1><<<grid, block, 0, stream>>>(Q, V, O, v16, vt16);
    } else {
        attn_f16<0><<<grid, block, 0, stream>>>(Q, V, O, nullptr, nullptr);
    }
}

// Round 20
// 934.043 us; speedup vs baseline: 1.1677x; 1.0033x over previous
//
#include <hip/hip_runtime.h>

// Fused flash-style softmax(Q V^T) V, B=4, NQ=NK=4096, D=1024, fp32 in/out.
// Round 20: r17/r19 pipeline with BK=64 (NT=64): HALVES the per-tile block
// rendezvous count (barriers 128->64, softmax invocations 128->64), which the
// r16/r19 data identify as the dominant serial cost. S^T partials are stored
// fp16-packed (spart_h, 64 KB double-buffered) to fit LDS; softmax lane owns
// 4 adjacent k (s16x4 reads). PV runs as two 32-k chunks: chunk0 frags
// preloaded in region A, chunk1 loaded at region-B top under chunk0 MFMAs.
//   region A_i: QK^T(i,4 halves) -> spart_h[i&1] || vt16 chunk0(i-1) || softmax(i-1)
//   barrier_i
//   region B_i: PV(i-1) chunks 0,1   (flows into A_{i+1}, no barrier)

#define NB   4
#define NQL  4096
#define NKL  4096
#define DIM  1024
#define BQ   32
#define BK   64
#define NW   8
#define DSL  128
#define NT   (NKL / BK)    // 64
#define LOG2E 1.44269504088896340736f
#define PBW  72            // pbuf row stride in shorts (144 B, 16B-aligned)

typedef float f32x4 __attribute__((ext_vector_type(4)));
typedef _Float16 f16x8 __attribute__((ext_vector_type(8)));
typedef short s16x8 __attribute__((ext_vector_type(8)));
typedef short s16x4 __attribute__((ext_vector_type(4)));

union Frag  { f16x8 v; s16x8 s; _Float16 h[8]; };
union Half4 { s16x4 s; _Float16 h[4]; };

__device__ __forceinline__ void rawbar() {  // LDS visibility only
    asm volatile("s_waitcnt lgkmcnt(0)\n\ts_barrier" ::: "memory");
}

// ---------------- Prepass: V fp32 -> V16 (row-major) + VT16 (transposed) -----
__global__ void prep_v(const float* __restrict__ Vg, short* __restrict__ v16,
                       short* __restrict__ vt16) {
    __shared__ short lds[64][72];
    const int t   = (int)threadIdx.x;
    const int blk = (int)blockIdx.x;
    const int bb    = blk >> 10;
    const int ktile = (blk >> 4) & 63;
    const int dtile = blk & 15;
    const int k0 = ktile * 64, d0 = dtile * 64;
    const int row = t >> 2;
    const int cb  = (t & 3) * 16;

    const float* src = Vg + ((size_t)(bb * NKL + k0 + row) * DIM + d0 + cb);
    short* vdst = v16 + ((size_t)(bb * NKL + k0 + row) * DIM + d0 + cb);
#pragma unroll
    for (int i = 0; i < 4; ++i) {
        f32x4 x = *(const f32x4*)(src + i * 4);
        s16x4 h;
#pragma unroll
        for (int j = 0; j < 4; ++j)
            h[j] = __builtin_bit_cast(short, (_Float16)x[j]);
        *(s16x4*)(vdst + i * 4) = h;
        *(s16x4*)&lds[row][cb + i * 4] = h;
    }
    __syncthreads();
    short* tdst = vt16 + ((size_t)(bb * DIM + d0 + row) * NKL + k0 + cb);
#pragma unroll
    for (int i = 0; i < 4; ++i) {
        s16x4 h;
#pragma unroll
        for (int j = 0; j < 4; ++j)
            h[j] = lds[cb + i * 4 + j][row];
        *(s16x4*)(tdst + i * 4) = h;
    }
}

// ---------------- Main kernel (MODE 1 = fp16 prepass; MODE 0 = fp32 direct) --
template<int MODE>
__global__ __attribute__((amdgpu_flat_work_group_size(512, 512),
                          amdgpu_waves_per_eu(1, 4)))
void attn_f16(const float* __restrict__ Qg, const float* __restrict__ Vg,
              float* __restrict__ Og, const short* __restrict__ v16,
              const short* __restrict__ vt16) {
    __shared__ __align__(16) short spart_h[2][NW][BQ][BK];  // 64 KB, fp16 partials
    __shared__ __align__(16) short pbuf[2][BQ * PBW];       // 9216 B
    __shared__ float arun[2][BQ];
    __shared__ float lsum[BQ];

    const int tid = (int)threadIdx.x;
    const int l   = tid & 63;
    const int w   = tid >> 6;
    const int l15 = l & 15;
    const int lg  = l >> 4;

    // XCD-aware swizzle (512 blocks, 8 XCDs, bijective)
    const int bid  = (int)blockIdx.x;
    const int orig = (bid & 7) * 64 + (bid >> 3);
    const int b  = orig >> 7;
    const int qt = orig & 127;
    const int q0 = qt * BQ;
    const int dw = w * DSL;

    // Q fragments (B-operand), fp32->fp16 once per block
    f16x8 qf[2][4];
#pragma unroll
    for (int qb = 0; qb < 2; ++qb)
#pragma unroll
        for (int dc = 0; dc < 4; ++dc) {
            const float* qp = Qg + (size_t)(b * NQL + q0 + qb * 16 + l15) * DIM
                            + dw + dc * 32 + lg * 8;
            f32x4 x0 = *(const f32x4*)qp;
            f32x4 x1 = *(const f32x4*)(qp + 4);
            f16x8 a;
#pragma unroll
            for (int j = 0; j < 4; ++j) { a[j] = (_Float16)x0[j]; a[j + 4] = (_Float16)x1[j]; }
            qf[qb][dc] = a;
        }

    f32x4 oacc[2][8];
#pragma unroll
    for (int qb = 0; qb < 2; ++qb)
#pragma unroll
        for (int dg = 0; dg < 8; ++dg)
            oacc[qb][dg] = (f32x4){0.f, 0.f, 0.f, 0.f};

    f32x4 sacc[4][2];               // 4 k-halves x 2 q-blocks
    s16x8 hst[2][4];                // MODE 1 staging, 2 ping-pong buffers
    f32x4 hst32[2][4][2];           // MODE 0 staging

    auto loadstage = [&](int buf, int kt_, int kb) {
        if constexpr (MODE == 1) {
            const short* vp = v16 + ((size_t)(b * NKL + kt_ * BK + kb * 16 + l15) * DIM
                            + dw + lg * 8);
#pragma unroll
            for (int dc = 0; dc < 4; ++dc)
                hst[buf][dc] = *(const s16x8*)(vp + dc * 32);
        } else {
            const float* vp = Vg + (size_t)(b * NKL + kt_ * BK + kb * 16 + l15) * DIM
                            + dw + lg * 8;
#pragma unroll
            for (int dc = 0; dc < 4; ++dc) {
                hst32[buf][dc][0] = *(const f32x4*)(vp + dc * 32);
                hst32[buf][dc][1] = *(const f32x4*)(vp + dc * 32 + 4);
            }
        }
    };

    auto qkt_half = [&](int buf, int kb) {
#pragma unroll
        for (int dc = 0; dc < 4; ++dc) {
            Frag fa;
            if constexpr (MODE == 1) {
                fa.s = hst[buf][dc];
            } else {
#pragma unroll
                for (int j = 0; j < 4; ++j) {
                    fa.h[j]     = (_Float16)hst32[buf][dc][0][j];
                    fa.h[j + 4] = (_Float16)hst32[buf][dc][1][j];
                }
            }
            sacc[kb][0] = __builtin_amdgcn_mfma_f32_16x16x32_f16(fa.v, qf[0][dc], sacc[kb][0], 0, 0, 0);
            sacc[kb][1] = __builtin_amdgcn_mfma_f32_16x16x32_f16(fa.v, qf[1][dc], sacc[kb][1], 0, 0, 0);
        }
    };

    auto qkt_tile = [&](int kt_, int spbuf) {
#pragma unroll
        for (int kb = 0; kb < 4; ++kb)
#pragma unroll
            for (int qb = 0; qb < 2; ++qb)
                sacc[kb][qb] = (f32x4){0.f, 0.f, 0.f, 0.f};
        const int ktn = (kt_ + 1 < NT) ? kt_ + 1 : NT - 1;
        // 4 k-halves through 2 staging buffers; final 2 loads prefetch tile ktn
        qkt_half(0, 0);  loadstage(0, kt_, 2);
        qkt_half(1, 1);  loadstage(1, kt_, 3);
        qkt_half(0, 2);  loadstage(0, ktn, 0);
        qkt_half(1, 3);  loadstage(1, ktn, 1);
        // S^T partials -> spart_h, fp16-packed s16x4 at XOR-swizzled k-group
#pragma unroll
        for (int kb = 0; kb < 4; ++kb)
#pragma unroll
            for (int qb = 0; qb < 2; ++qb) {
                const int q = qb * 16 + l15;
                const int kblk = (kb * 16 + lg * 4) ^ ((q & 7) << 2);
                Half4 pk;
#pragma unroll
                for (int r = 0; r < 4; ++r)
                    pk.h[r] = (_Float16)sacc[kb][qb][r];
                *(s16x4*)&spart_h[spbuf][w][q][kblk] = pk.s;
            }
    };

    // softmax: lane group handles q = 4w+lg, adjacent k-quad {4*l15 .. +3}
    const int qsm = 4 * w + lg;
    const int kk  = (4 * l15) ^ ((qsm & 7) << 2);

    float m_reg  = -3e38f;
    float l_lane = 0.f;

    auto softmax_tile = [&](int cur) {
        float s[4] = {0.f, 0.f, 0.f, 0.f};
#pragma unroll
        for (int wv = 0; wv < NW; ++wv) {
            Half4 hp;
            hp.s = *(const s16x4*)&spart_h[cur][wv][qsm][kk];
#pragma unroll
            for (int r = 0; r < 4; ++r)
                s[r] += (float)hp.h[r];
        }
        float smax = fmaxf(fmaxf(s[0], s[1]), fmaxf(s[2], s[3]));
        float alpha = 1.0f;
        if (!__all(smax - m_reg <= 8.0f)) {
            float mloc = smax;
#pragma unroll
            for (int off = 1; off < 16; off <<= 1)
                mloc = fmaxf(mloc, __shfl_xor(mloc, off));
            float mnew = fmaxf(m_reg, mloc);
            alpha = exp2f((m_reg - mnew) * LOG2E);
            m_reg = mnew;
        }
        float psum = 0.f;
        Half4 pk;
#pragma unroll
        for (int r = 0; r < 4; ++r) {
            float p = exp2f((s[r] - m_reg) * LOG2E);
            psum += p;
            pk.h[r] = (_Float16)p;
        }
        l_lane = alpha * l_lane + psum;
        if (l15 == 0) arun[cur][qsm] = alpha;
        *(s16x4*)&pbuf[cur][qsm * PBW + 4 * l15] = pk.s;
    };

    s16x8 pvreg[8];                 // MODE 1: chunk-0 vt16 frags (region A)

    auto pv_loads = [&](int kt_) {
        if constexpr (MODE == 1) {
            const short* vtb = vt16 + ((size_t)(b * DIM + dw + l15) * NKL
                             + kt_ * BK + lg * 8);
#pragma unroll
            for (int dg = 0; dg < 8; ++dg)
                pvreg[dg] = *(const s16x8*)(vtb + (size_t)dg * 16 * NKL);
        }
    };

    auto pv_tile = [&](int kt_, int cur) {
        // chunk-1 loads first: latency hides under rescale + chunk-0 MFMAs
        s16x8 pv1[8];
        if constexpr (MODE == 1) {
            const short* vtb = vt16 + ((size_t)(b * DIM + dw + l15) * NKL
                             + kt_ * BK + lg * 8);
#pragma unroll
            for (int dg = 0; dg < 8; ++dg)
                pv1[dg] = *(const s16x8*)(vtb + (size_t)dg * 16 * NKL + 32);
        }
        f32x4 av[2];
#pragma unroll
        for (int qb = 0; qb < 2; ++qb)
            av[qb] = *(const f32x4*)&arun[cur][qb * 16 + lg * 4];
        bool mine1 = true;
#pragma unroll
        for (int qb = 0; qb < 2; ++qb)
#pragma unroll
            for (int r = 0; r < 4; ++r)
                mine1 = mine1 && (av[qb][r] == 1.0f);
        if (!__all(mine1)) {
#pragma unroll
            for (int qb = 0; qb < 2; ++qb)
#pragma unroll
                for (int dg = 0; dg < 8; ++dg)
#pragma unroll
                    for (int r = 0; r < 4; ++r)
                        oacc[qb][dg][r] *= av[qb][r];
        }
        Frag pf[2][2];
#pragma unroll
        for (int qb = 0; qb < 2; ++qb)
#pragma unroll
            for (int c = 0; c < 2; ++c)
                pf[qb][c].s = *(const s16x8*)&pbuf[cur][(qb * 16 + l15) * PBW
                                                        + c * 32 + lg * 8];
        if constexpr (MODE == 1) {
#pragma unroll
            for (int dg = 0; dg < 8; ++dg) {
                __builtin_amdgcn_s_setprio(1);
#pragma unroll
                for (int qb = 0; qb < 2; ++qb)
                    oacc[qb][dg] = __builtin_amdgcn_mfma_f32_16x16x32_f16(
                        pf[qb][0].v, (Frag{.s = pvreg[dg]}).v, oacc[qb][dg], 0, 0, 0);
                __builtin_amdgcn_s_setprio(0);
            }
#pragma unroll
            for (int dg = 0; dg < 8; ++dg) {
                __builtin_amdgcn_s_setprio(1);
#pragma unroll
                for (int qb = 0; qb < 2; ++qb)
                    oacc[qb][dg] = __builtin_amdgcn_mfma_f32_16x16x32_f16(
                        pf[qb][1].v, (Frag{.s = pv1[dg]}).v, oacc[qb][dg], 0, 0, 0);
                __builtin_amdgcn_s_setprio(0);
            }
        } else {
            // fp32 gather fallback, chunk by chunk
#pragma unroll
            for (int c = 0; c < 2; ++c) {
                const float* vb = Vg + (size_t)(b * NKL + kt_ * BK + c * 32 + lg * 8) * DIM
                                + dw + l15;
#pragma unroll
                for (int dg = 0; dg < 8; ++dg) {
                    Frag bf;
#pragma unroll
                    for (int j = 0; j < 8; ++j)
                        bf.h[j] = (_Float16)vb[(size_t)j * DIM + dg * 16];
#pragma unroll
                    for (int qb = 0; qb < 2; ++qb)
                        oacc[qb][dg] = __builtin_amdgcn_mfma_f32_16x16x32_f16(
                            pf[qb][c].v, bf.v, oacc[qb][dg], 0, 0, 0);
                }
            }
        }
    };

    // ---- Prologue: stage tile 0 (kb0,kb1), QK^T(0) -> spart_h[0], barrier
    loadstage(0, 0, 0);
    loadstage(1, 0, 1);
    qkt_tile(0, 0);
    rawbar();

    // ---- Pipelined main loop: one barrier per 64-k tile
    for (int kt = 1; kt < NT; ++kt) {
        const int cur = (kt - 1) & 1;
        pv_loads(kt - 1);
        qkt_tile(kt, kt & 1);
        softmax_tile(cur);
        rawbar();
        pv_tile(kt - 1, cur);
    }

    // ---- Tail: softmax + PV for tile NT-1
    {
        const int cur = (NT - 1) & 1;
        pv_loads(NT - 1);
        softmax_tile(cur);
        rawbar();
        pv_tile(NT - 1, cur);
    }

    // ---- Epilogue: reduce l across the 16-lane group, normalize, store
    {
        float rs = l_lane;
#pragma unroll
        for (int off = 1; off < 16; off <<= 1)
            rs += __shfl_xor(rs, off);
        if (l15 == 0) lsum[qsm] = rs;
    }
    __syncthreads();
#pragma unroll
    for (int qb = 0; qb < 2; ++qb) {
        f32x4 lv = *(const f32x4*)&lsum[qb * 16 + lg * 4];
        float il[4];
#pragma unroll
        for (int r = 0; r < 4; ++r) il[r] = 1.0f / lv[r];
#pragma unroll
        for (int dg = 0; dg < 8; ++dg)
#pragma unroll
            for (int r = 0; r < 4; ++r) {
                int q = q0 + qb * 16 + lg * 4 + r;
                int d = dw + dg * 16 + l15;
                Og[(size_t)(b * NQL + q) * DIM + d] = oacc[qb][dg][r] * il[r];
            }
    }
}

extern "C" void kernel_launch(void* const* d_in, const int* in_sizes, int n_in,
                              void* d_out, int out_size, void* d_ws, size_t ws_size,
                              hipStream_t stream) {
    const float* Q = (const float*)d_in[0];
    const float* V = (const float*)d_in[1];
    float* O = (float*)d_out;
    (void)in_sizes; (void)n_in; (void)out_size;

    const size_t elems = (size_t)NB * NKL * DIM;          // 16.78M
    const size_t need  = 2 * elems * sizeof(short);       // 64 MB
    dim3 grid(NB * (NQL / BQ));  // 512 blocks
    dim3 block(NW * 64);         // 512 threads
    if (ws_size >= need) {
        short* v16  = (short*)d_ws;
        short* vt16 = v16 + elems;
        prep_v<<<dim3(NB * 1024), dim3(256), 0, stream>>>(V, v16, vt16);
        attn_f16<1><<<grid, block, 0, stream>>>(Q, V, O, v16, vt16);
    } else {
        attn_f16<0><<<grid, block, 0, stream>>>(Q, V, O, nullptr, nullptr);
    }
}